// Round 1
// baseline (2066.764 us; speedup 1.0000x reference)
//
#include <hip/hip_runtime.h>

#define BQ   16
#define CINC 8
#define SEQ  32
#define HH   128
#define WW   128
#define COUTC 8
#define GATES 32      // 4*Cout
#define ICH  16       // Cin+Cout
#define TH   4        // rows per tile
#define LDS_H 6       // TH+2
#define LDS_W 132     // 128+2 halo, +2 pad

__device__ __forceinline__ float fast_rcp(float x) { return __builtin_amdgcn_rcpf(x); }
__device__ __forceinline__ float sigmoidf_(float x) {
    return fast_rcp(1.0f + __expf(-x));
}
__device__ __forceinline__ float tanhf_(float x) {
    float e = __expf(-2.0f * x);
    return (1.0f - e) * fast_rcp(1.0f + e);
}

// Wc layout [oc][ic][ky][kx] (oc<32, ic<16) -> Wt[(ic*3+ky)*3+kx][oc]
__global__ void transpose_w(const float* __restrict__ Wc, float* __restrict__ Wt) {
    int i = blockIdx.x * 256 + threadIdx.x;
    if (i >= GATES * ICH * 9) return;
    int oc = i / (ICH * 9);
    int r  = i % (ICH * 9);
    Wt[r * GATES + oc] = Wc[i];
}

__global__ __launch_bounds__(256, 2) void step_kernel(
    const float* __restrict__ X,    // (B, Cin, S, H, W)
    const float* __restrict__ Wt,   // (144, 32)
    const float* __restrict__ bc,   // (32,)
    float* __restrict__ out,        // (B, Cout, S, H, W)
    float* __restrict__ c,          // (B, Cout, H, W)
    int t)
{
    __shared__ float lds[ICH * LDS_H * LDS_W];

    const int blk = blockIdx.x;     // 0..511
    const int b   = blk >> 5;       // batch
    const int rt  = blk & 31;       // row tile
    const int r0  = rt * TH;
    const int tid = threadIdx.x;

    // ---- stage x (ch 0..7) and h_prev (ch 8..15) tiles into LDS ----
    const int NLOAD = ICH * LDS_H * (WW + 2);   // 16*6*130 = 12480
    for (int idx = tid; idx < NLOAD; idx += 256) {
        int ch  = idx / (LDS_H * (WW + 2));
        int rem = idx % (LDS_H * (WW + 2));
        int row = rem / (WW + 2);
        int col = rem % (WW + 2);
        int y = r0 + row - 1;
        int x = col - 1;
        float v = 0.0f;
        if ((unsigned)y < HH && (unsigned)x < WW) {
            if (ch < CINC) {
                v = X[(((size_t)(b * CINC + ch) * SEQ + t) * HH + y) * WW + x];
            } else if (t > 0) {
                v = out[(((size_t)(b * COUTC + (ch - CINC)) * SEQ + (t - 1)) * HH + y) * WW + x];
            }
        }
        lds[(ch * LDS_H + row) * LDS_W + col] = v;
    }
    __syncthreads();

    // ---- conv: 2 pixels per thread (cols tx and tx+64), 32 gate accumulators each ----
    const int tx = tid & 63;
    const int ty = tid >> 6;   // 0..3

    float acc0[GATES];
    float acc1[GATES];
#pragma unroll
    for (int g = 0; g < GATES; ++g) { acc0[g] = 0.0f; acc1[g] = 0.0f; }

    for (int ic = 0; ic < ICH; ++ic) {
#pragma unroll
        for (int ky = 0; ky < 3; ++ky) {
            const float* ldsrow = &lds[(ic * LDS_H + ty + ky) * LDS_W];
#pragma unroll
            for (int kx = 0; kx < 3; ++kx) {
                float a0 = ldsrow[tx + kx];
                float a1 = ldsrow[tx + 64 + kx];
                const float* wp = Wt + ((ic * 3 + ky) * 3 + kx) * GATES;
#pragma unroll
                for (int g = 0; g < GATES; ++g) {
                    float w = wp[g];
                    acc0[g] += w * a0;
                    acc1[g] += w * a1;
                }
            }
        }
    }

    // ---- gates, state update, write h and c ----
    const int y = r0 + ty;
#pragma unroll
    for (int oc = 0; oc < COUTC; ++oc) {
        float bi = bc[oc], bf = bc[oc + 8], bg = bc[oc + 16], bo = bc[oc + 24];
        size_t cidx = (((size_t)(b * COUTC + oc) * HH + y) * WW);
        size_t oidx = (((size_t)(b * COUTC + oc) * SEQ + t) * HH + y) * WW;

        // pixel 0: col = tx
        {
            float zi = acc0[oc] + bi;
            float zf = acc0[oc + 8] + bf;
            float zg = acc0[oc + 16] + bg;
            float zo = acc0[oc + 24] + bo;
            float cp = (t > 0) ? c[cidx + tx] : 0.0f;
            float cn = sigmoidf_(zf) * cp + sigmoidf_(zi) * tanhf_(zg);
            c[cidx + tx] = cn;
            out[oidx + tx] = sigmoidf_(zo) * tanhf_(cn);
        }
        // pixel 1: col = tx + 64
        {
            float zi = acc1[oc] + bi;
            float zf = acc1[oc + 8] + bf;
            float zg = acc1[oc + 16] + bg;
            float zo = acc1[oc + 24] + bo;
            float cp = (t > 0) ? c[cidx + tx + 64] : 0.0f;
            float cn = sigmoidf_(zf) * cp + sigmoidf_(zi) * tanhf_(zg);
            c[cidx + tx + 64] = cn;
            out[oidx + tx + 64] = sigmoidf_(zo) * tanhf_(cn);
        }
    }
}

extern "C" void kernel_launch(void* const* d_in, const int* in_sizes, int n_in,
                              void* d_out, int out_size, void* d_ws, size_t ws_size,
                              hipStream_t stream) {
    const float* X  = (const float*)d_in[0];
    const float* Wc = (const float*)d_in[1];
    const float* bc = (const float*)d_in[2];
    float* out = (float*)d_out;

    float* Wt = (float*)d_ws;                       // 4608 floats
    float* c  = (float*)d_ws + 4608;                // 16*8*128*128 floats (8.4 MB)

    transpose_w<<<18, 256, 0, stream>>>(Wc, Wt);
    for (int t = 0; t < SEQ; ++t) {
        step_kernel<<<512, 256, 0, stream>>>(X, Wt, bc, out, c, t);
    }
}

// Round 2
// 904.221 us; speedup vs baseline: 2.2857x; 2.2857x over previous
//
#include <hip/hip_runtime.h>

#define SEQ   32
#define HH    128
#define WW    128
#define CINC  8
#define COUTC 8
#define NG    32      // 4*Cout gates
#define ICH   16      // Cin+Cout
#define TAPS  9
#define ROWS  4       // 2 output rows + halo
#define COLS  130     // 128 + halo

typedef _Float16 half8 __attribute__((ext_vector_type(8)));
typedef float floatx16 __attribute__((ext_vector_type(16)));

__device__ __forceinline__ float fast_rcp(float x) { return __builtin_amdgcn_rcpf(x); }
__device__ __forceinline__ float sigmoidf_(float x) {
    return fast_rcp(1.0f + __expf(-x));
}
__device__ __forceinline__ float tanhf_(float x) {
    float e = __expf(-2.0f * x);
    return (1.0f - e) * fast_rcp(1.0f + e);
}

// Wc[g][ic][ky][kx] fp32 -> Wf[tap][gate][ch_half][8ch] f16 (A-operand fragments)
__global__ void prep_weights(const float* __restrict__ Wc, _Float16* __restrict__ Wf) {
    int i = blockIdx.x * 256 + threadIdx.x;
    if (i >= TAPS * NG * ICH) return;
    int tap = i / (NG * ICH);
    int r   = i % (NG * ICH);
    int g   = r >> 4;
    int ch  = r & 15;
    int half = ch >> 3, c8 = ch & 7;
    int ky = tap / 3, kx = tap % 3;
    float w = Wc[g * (ICH * 9) + ch * 9 + ky * 3 + kx];
    Wf[((tap * NG + g) * 2 + half) * 8 + c8] = (_Float16)w;
}

__global__ __launch_bounds__(256, 4) void step_kernel(
    const float* __restrict__ X,      // (B, Cin, S, H, W)
    const _Float16* __restrict__ Wf,  // (9, 32, 2, 8)
    const float* __restrict__ bc,     // (32,)
    float* __restrict__ out,          // (B, Cout, S, H, W)
    float* __restrict__ c,            // (B, Cout, H, W)
    int t)
{
    __shared__ __align__(16) _Float16 ldsH[2 * ROWS * COLS * 8];
    __shared__ __align__(16) _Float16 ldsL[2 * ROWS * COLS * 8];

    const int tid = threadIdx.x;
    const int b   = blockIdx.x >> 6;
    const int y0  = (blockIdx.x & 63) * 2;

    // ---- stage x + h_prev as f16 hi/lo, layout [half][row][col][8ch] ----
    for (int idx = tid; idx < 2 * ROWS * COLS; idx += 256) {
        int col  = idx % COLS;
        int tmp  = idx / COLS;     // 0..7
        int half = tmp >> 2;
        int row  = tmp & 3;
        int gy = y0 + row - 1;
        int gx = col - 1;
        bool inb = ((unsigned)gy < HH) && ((unsigned)gx < WW);
        float v[8];
#pragma unroll
        for (int j = 0; j < 8; ++j) {
            int ch = half * 8 + j;
            float val = 0.0f;
            if (inb) {
                if (ch < CINC)
                    val = X[(((size_t)(b * CINC + ch) * SEQ + t) * HH + gy) * WW + gx];
                else if (t > 0)
                    val = out[(((size_t)(b * COUTC + (ch - 8)) * SEQ + (t - 1)) * HH + gy) * WW + gx];
            }
            v[j] = val;
        }
        union { half8 h; float4 f; } uh, ul;
#pragma unroll
        for (int j = 0; j < 8; ++j) {
            _Float16 hi = (_Float16)v[j];
            uh.h[j] = hi;
            ul.h[j] = (_Float16)(v[j] - (float)hi);
        }
        // lds index = ((half*ROWS + row)*COLS + col)*8  == idx*8
        *(float4*)&ldsH[(size_t)idx * 8] = uh.f;
        *(float4*)&ldsL[(size_t)idx * 8] = ul.f;
    }

    const int lane = tid & 63;
    const int w    = tid >> 6;       // wave 0..3
    const int lg   = lane & 31;      // A: gate row; B: pixel col
    const int lh   = lane >> 5;      // ch half / k-group

    // ---- weight A-fragments (held in VGPRs, 36 regs) ----
    half8 wfrag[TAPS];
#pragma unroll
    for (int tap = 0; tap < TAPS; ++tap)
        wfrag[tap] = *(const half8*)&Wf[((tap * NG + lg) * 2 + lh) * 8];

    __syncthreads();

    // ---- MFMA main loop: wave covers row ry, cols x0..x0+63 (2 N-tiles) ----
    const int ry = w >> 1;           // 0..1
    const int x0 = (w & 1) * 64;

    floatx16 acc0, acc1;
#pragma unroll
    for (int r = 0; r < 16; ++r) { acc0[r] = 0.0f; acc1[r] = 0.0f; }

#pragma unroll
    for (int tap = 0; tap < TAPS; ++tap) {
        int ky = tap / 3, kx = tap % 3;
        int row = ry + ky;
        int base0 = ((lh * ROWS + row) * COLS + (x0 + lg + kx)) * 8;
        int base1 = base0 + 32 * 8;
        half8 bh0 = *(const half8*)&ldsH[base0];
        half8 bl0 = *(const half8*)&ldsL[base0];
        half8 bh1 = *(const half8*)&ldsH[base1];
        half8 bl1 = *(const half8*)&ldsL[base1];
        acc0 = __builtin_amdgcn_mfma_f32_32x32x16_f16(wfrag[tap], bh0, acc0, 0, 0, 0);
        acc1 = __builtin_amdgcn_mfma_f32_32x32x16_f16(wfrag[tap], bh1, acc1, 0, 0, 0);
        acc0 = __builtin_amdgcn_mfma_f32_32x32x16_f16(wfrag[tap], bl0, acc0, 0, 0, 0);
        acc1 = __builtin_amdgcn_mfma_f32_32x32x16_f16(wfrag[tap], bl1, acc1, 0, 0, 0);
    }

    // ---- epilogue: lane holds gates {oc, oc+8, oc+16, oc+24} for oc = r + 4*lh ----
    const int y = y0 + ry;
#pragma unroll
    for (int tl = 0; tl < 2; ++tl) {
        floatx16 A = tl ? acc1 : acc0;
        int px = x0 + tl * 32 + lg;
#pragma unroll
        for (int r = 0; r < 4; ++r) {
            int oc = r + 4 * lh;
            float zi = A[r]      + bc[oc];
            float zf = A[4 + r]  + bc[oc + 8];
            float zg = A[8 + r]  + bc[oc + 16];
            float zo = A[12 + r] + bc[oc + 24];
            size_t ci = ((size_t)(b * COUTC + oc) * HH + y) * WW + px;
            float cp = (t > 0) ? c[ci] : 0.0f;
            float cn = sigmoidf_(zf) * cp + sigmoidf_(zi) * tanhf_(zg);
            c[ci] = cn;
            out[(((size_t)(b * COUTC + oc) * SEQ + t) * HH + y) * WW + px]
                = sigmoidf_(zo) * tanhf_(cn);
        }
    }
}

extern "C" void kernel_launch(void* const* d_in, const int* in_sizes, int n_in,
                              void* d_out, int out_size, void* d_ws, size_t ws_size,
                              hipStream_t stream) {
    const float* X  = (const float*)d_in[0];
    const float* Wc = (const float*)d_in[1];
    const float* bc = (const float*)d_in[2];
    float* out = (float*)d_out;

    _Float16* Wf = (_Float16*)d_ws;                           // 4608 f16 = 9216 B
    float* c = (float*)((char*)d_ws + 16384);                 // 8.39 MB c-state

    prep_weights<<<(TAPS * NG * ICH + 255) / 256, 256, 0, stream>>>(Wc, Wf);
    for (int t = 0; t < SEQ; ++t) {
        step_kernel<<<16 * 64, 256, 0, stream>>>(X, Wf, bc, out, c, t);
    }
}